// Round 10
// baseline (204.198 us; speedup 1.0000x reference)
//
#include <hip/hip_runtime.h>
#include <hip/hip_bf16.h>
#include <stdint.h>

#define BS 4
#define NS 4096
#define NT 16384
#define CT 128
#define NOUT 256
#define MTOT (BS*NT) // 65536
#define GR 8
#define NC (GR*GR*GR)
#define HCELL 0.125f

typedef __attribute__((ext_vector_type(4))) float floatx4;
typedef __attribute__((ext_vector_type(8))) unsigned short ushortx8;
typedef __attribute__((ext_vector_type(8))) __bf16 bf16x8;

__device__ __forceinline__ unsigned short f2bf(float f) {
  unsigned int u = __builtin_bit_cast(unsigned int, f);
  u += 0x7FFFu + ((u >> 16) & 1u);
  return (unsigned short)(u >> 16);
}
__device__ __forceinline__ float bf2f(unsigned short u) {
  return __builtin_bit_cast(float, ((unsigned int)u) << 16);
}
__device__ __forceinline__ int cell_of(float x) {
  int c = (int)(x * 8.0f);
  return min(7, max(0, c));
}
__device__ __forceinline__ bf16x8 ldb16(const unsigned short* p) {
  return __builtin_bit_cast(bf16x8, *(const ushortx8*)p);
}
__device__ __forceinline__ ushortx8 wsum8(ushortx8 a, ushortx8 c, ushortx8 e,
                                          float w0, float w1v, float w2v) {
  ushortx8 o;
  #pragma unroll
  for (int q = 0; q < 8; ++q)
    o[q] = f2bf(w0*bf2f(a[q]) + w1v*bf2f(c[q]) + w2v*bf2f(e[q]));
  return o;
}

// pinned 16B global load: asm volatile cannot be sunk/serialized by the scheduler
#define GLD16(dst, ptr, off) \
  asm volatile("global_load_dwordx4 %0, %1, off offset:" #off \
               : "=&v"(dst) : "v"(ptr))

// ---------------- prep (round-6 version) ----------------
__global__ __launch_bounds__(1024) void prep_kernel(
    const float* __restrict__ xyzs, const float* __restrict__ xyzt,
    const float* __restrict__ w1, const float* __restrict__ w2,
    float4* __restrict__ bsrc, int* __restrict__ soff, float4* __restrict__ stgt,
    unsigned short* __restrict__ w1at, unsigned short* __restrict__ w1bt,
    unsigned short* __restrict__ w2t) {
  int bid = blockIdx.x, tid = threadIdx.x;
  if (bid < 8) {
    __shared__ int cnt[NC];
    __shared__ int wtot[16];
    int b = bid & 3;
    bool isrc = bid < 4;
    int per = isrc ? (NS >> 10) : (NT >> 10);
    const float* in = isrc ? xyzs + (size_t)b * NS * 3 : xyzt + (size_t)b * NT * 3;
    float4* outp = isrc ? bsrc + (size_t)b * NS : stgt + (size_t)b * NT;
    if (tid < NC) cnt[tid] = 0;
    __syncthreads();
    for (int k = 0; k < per; ++k) {
      int p = k * 1024 + tid;
      float x = in[3*p], y = in[3*p+1], z = in[3*p+2];
      int c = (cell_of(z) * GR + cell_of(y)) * GR + cell_of(x);
      atomicAdd(&cnt[c], 1);
    }
    __syncthreads();
    int l = tid & 63, w = tid >> 6;
    int v = (tid < NC) ? cnt[tid] : 0;
    #pragma unroll
    for (int d = 1; d < 64; d <<= 1) {
      int t = __shfl_up(v, d);
      if (l >= d) v += t;
    }
    if (l == 63 && w < 8) wtot[w] = v;
    __syncthreads();
    if (w == 0 && l < 8) {
      int s = wtot[l];
      #pragma unroll
      for (int d = 1; d < 8; d <<= 1) {
        int t = __shfl_up(s, d);
        if (l >= d) s += t;
      }
      wtot[l] = s;
    }
    __syncthreads();
    if (tid < NC) {
      int incl = v + (w > 0 ? wtot[w-1] : 0);
      int excl = incl - cnt[tid];
      cnt[tid] = excl;
      if (isrc) soff[b * (NC + 1) + tid] = excl;
    }
    if (isrc && tid == 0) soff[b * (NC + 1) + NC] = NS;
    __syncthreads();
    for (int k = 0; k < per; ++k) {
      int p = k * 1024 + tid;
      float x = in[3*p], y = in[3*p+1], z = in[3*p+2];
      int c = (cell_of(z) * GR + cell_of(y)) * GR + cell_of(x);
      int slot = atomicAdd(&cnt[c], 1);
      outp[slot] = make_float4(x, y, z, __int_as_float(p));
    }
  } else {
    int i = (bid - 8) * 1024 + tid;  // i < 65536
    int n = i >> 8, k = i & 255;
    w1at[i] = f2bf(w1[k * NOUT + n]);
    w2t[i]  = f2bf(w2[k * NOUT + n]);
    if (i < 256 * 128) {
      int n2 = i >> 7, k2 = i & 127;
      w1bt[i] = f2bf(w1[(256 + k2) * NOUT + n2]);
    }
  }
}

// ---------------- three_nn helpers ----------------
__device__ __forceinline__ void ins3(float sc, int jj,
    float& d0, float& d1, float& d2, int& i0, int& i1, int& i2) {
  bool l0 = sc < d0, l1 = sc < d1, l2 = sc < d2;
  d2 = l1 ? d1 : (l2 ? sc : d2);
  i2 = l1 ? i1 : (l2 ? jj : i2);
  d1 = l0 ? d0 : (l1 ? sc : d1);
  i1 = l0 ? i0 : (l1 ? jj : i1);
  d0 = l0 ? sc : d0;
  i0 = l0 ? jj : i0;
}

__device__ __forceinline__ void pair_merge(float& d0, float& d1, float& d2,
                                           int& i0, int& i1, int& i2,
                                           int delta, int sub) {
  float e0 = __shfl_xor(d0, delta);
  float e1 = __shfl_xor(d1, delta);
  float e2 = __shfl_xor(d2, delta);
  int   y0 = __shfl_xor(i0, delta);
  int   y1 = __shfl_xor(i1, delta);
  int   y2 = __shfl_xor(i2, delta);
  float a0,a1,a2,b0,b1,b2; int x0,x1,x2,z0,z1,z2;
  if ((sub & delta) == 0) { a0=d0;a1=d1;a2=d2; x0=i0;x1=i1;x2=i2;
                            b0=e0;b1=e1;b2=e2; z0=y0;z1=y1;z2=y2; }
  else                    { a0=e0;a1=e1;a2=e2; x0=y0;x1=y1;x2=y2;
                            b0=d0;b1=d1;b2=d2; z0=i0;z1=i1;z2=i2; }
  bool t = a0 <= b0;
  d0 = t ? a0 : b0; i0 = t ? x0 : z0;
  float na0 = t ? a1 : a0; int nx0 = t ? x1 : x0;
  float na1 = t ? a2 : a1; int nx1 = t ? x2 : x1;
  float nb0 = t ? b0 : b1; int nz0 = t ? z0 : z1;
  float nb1 = t ? b1 : b2; int nz1 = t ? z1 : z2;
  t = na0 <= nb0;
  d1 = t ? na0 : nb0; i1 = t ? nx0 : nz0;
  float ma0 = t ? na1 : na0; int mx0 = t ? nx1 : nx0;
  float mb0 = t ? nb0 : nb1; int mz0 = t ? nz0 : nz1;
  t = ma0 <= mb0;
  d2 = t ? ma0 : mb0; i2 = t ? mx0 : mz0;
}

// round-6 version (part of best-measured totals)
__global__ __launch_bounds__(256) void nn_kernel(const float4* __restrict__ stgt,
    const float4* __restrict__ bsrc, const int* __restrict__ soff,
    int* __restrict__ idx_out, float* __restrict__ w_out) {
  __shared__ float4 s_src[NS];
  __shared__ int s_off[NC + 1];
  __shared__ float4 s_badq[128];
  __shared__ int s_badn;
  int tid = threadIdx.x;
  int b = blockIdx.x >> 7;
  int tseg = blockIdx.x & 127;
  if (tid == 0) s_badn = 0;
  for (int i = tid; i < NS; i += 256) s_src[i] = bsrc[(size_t)b * NS + i];
  for (int i = tid; i < NC + 1; i += 256) s_off[i] = soff[b * (NC + 1) + i];
  __syncthreads();
  int tpair = tid >> 1, half = tid & 1;
  float4 tg = stgt[(size_t)b * NT + tseg * 128 + tpair];
  float tx = tg.x, ty = tg.y, tz = tg.z;
  int cx = cell_of(tx), cy = cell_of(ty), cz = cell_of(tz);
  int wx = min(max(cx, 1), 6) - 1;
  int wy = min(max(cy, 1), 6) - 1;
  int wz = min(max(cz, 1), 6) - 1;
  float d0 = 1e30f, d1 = 1e30f, d2 = 1e30f;
  int i0 = 0, i1 = 0, i2 = 0;
  for (int r = half; r < 9; r += 2) {
    int ez = wz + r / 3, ey = wy + r % 3;
    int rowc = (ez * GR + ey) * GR + wx;
    int lo = s_off[rowc], hi = s_off[rowc + 3];
    for (int p = lo; p < hi; ++p) {
      float4 s = s_src[p];
      float dx = tx - s.x, dy = ty - s.y, dz = tz - s.z;
      float q = dx*dx + dy*dy + dz*dz;
      ins3(q, __float_as_int(s.w), d0, d1, d2, i0, i1, i2);
    }
  }
  pair_merge(d0, d1, d2, i0, i1, i2, 1, half);
  float clx = fminf(wx > 0 ? tx - wx * HCELL : 1e30f,
                    wx + 3 < GR ? (wx + 3) * HCELL - tx : 1e30f);
  float cly = fminf(wy > 0 ? ty - wy * HCELL : 1e30f,
                    wy + 3 < GR ? (wy + 3) * HCELL - ty : 1e30f);
  float clz = fminf(wz > 0 ? tz - wz * HCELL : 1e30f,
                    wz + 3 < GR ? (wz + 3) * HCELL - tz : 1e30f);
  float cl = fminf(clx, fminf(cly, clz));
  bool bad = d2 > cl * cl;
  if (half == 0) {
    if (bad) {
      int slot = atomicAdd(&s_badn, 1);
      s_badq[slot] = make_float4(tx, ty, tz, __int_as_float(tseg * 128 + tpair));
    } else {
      float r0 = fmaxf(sqrtf(d0), 1e-10f);
      float r1 = fmaxf(sqrtf(d1), 1e-10f);
      float r2 = fmaxf(sqrtf(d2), 1e-10f);
      float v0 = 1.f/r0, v1 = 1.f/r1, v2 = 1.f/r2;
      float sc = 1.f / ((v0 + v1 + v2) * (1.f + 1e-6f));
      size_t o = ((size_t)b * NT + tseg * 128 + tpair) * 3;
      idx_out[o] = i0; idx_out[o+1] = i1; idx_out[o+2] = i2;
      w_out[o] = v0*sc; w_out[o+1] = v1*sc; w_out[o+2] = v2*sc;
    }
  }
  __syncthreads();
  int nbad = s_badn;
  int wv = tid >> 6, ln = tid & 63;
  for (int e = wv; e < nbad; e += 4) {
    float4 tq = s_badq[e];
    float qx = tq.x, qy = tq.y, qz = tq.z;
    float f0 = 1e30f, f1 = 1e30f, f2 = 1e30f;
    int   j0 = 0, j1 = 0, j2 = 0;
    for (int p = ln; p < NS; p += 64) {
      float4 s = s_src[p];
      float dx = qx - s.x, dy = qy - s.y, dz = qz - s.z;
      float q = dx*dx + dy*dy + dz*dz;
      ins3(q, __float_as_int(s.w), f0, f1, f2, j0, j1, j2);
    }
    #pragma unroll
    for (int delta = 1; delta <= 32; delta <<= 1)
      pair_merge(f0, f1, f2, j0, j1, j2, delta, ln);
    if (ln == 0) {
      float r0 = fmaxf(sqrtf(f0), 1e-10f);
      float r1 = fmaxf(sqrtf(f1), 1e-10f);
      float r2 = fmaxf(sqrtf(f2), 1e-10f);
      float v0 = 1.f/r0, v1 = 1.f/r1, v2 = 1.f/r2;
      float sc = 1.f / ((v0 + v1 + v2) * (1.f + 1e-6f));
      size_t o = ((size_t)b * NT + __float_as_int(tq.w)) * 3;
      idx_out[o] = j0; idx_out[o+1] = j1; idx_out[o+2] = j2;
      w_out[o] = v0*sc; w_out[o+1] = v1*sc; w_out[o+2] = v2*sc;
    }
  }
}

// ---------------- G = fs @ W1a  (bf16 out, no relu) ---------------- (round-6 version)
__global__ __launch_bounds__(256, 4) void gemm_g(const float* __restrict__ fs,
    const unsigned short* __restrict__ w1at, unsigned short* __restrict__ G) {
  constexpr int LDT = 264;  // 256 + 8 pad
  __shared__ __attribute__((aligned(16))) unsigned short sA[32 * LDT];
  int tid = threadIdx.x;
  int m0 = blockIdx.x * 32;
  int wave = tid >> 6, lane = tid & 63;
  int wn = wave * 64;
  int fr = lane & 15, quad = lane >> 4;
  const unsigned short* wbase = w1at + (size_t)(wn + fr) * 256 + quad * 8;
  #pragma unroll
  for (int i = 0; i < 4; ++i) {
    int u = tid + 256 * i;
    int r = u >> 5, k8 = (u & 31) * 8;
    const float* src = fs + (size_t)(m0 + r) * 256 + k8;
    float4 f0 = *(const float4*)src;
    float4 f1 = *(const float4*)(src + 4);
    ushortx8 o;
    o[0]=f2bf(f0.x); o[1]=f2bf(f0.y); o[2]=f2bf(f0.z); o[3]=f2bf(f0.w);
    o[4]=f2bf(f1.x); o[5]=f2bf(f1.y); o[6]=f2bf(f1.z); o[7]=f2bf(f1.w);
    *(ushortx8*)&sA[r * LDT + k8] = o;
  }
  __syncthreads();
  floatx4 zero = {0.f, 0.f, 0.f, 0.f};
  floatx4 acc[2][4];
  #pragma unroll
  for (int i = 0; i < 2; ++i)
    #pragma unroll
    for (int j = 0; j < 4; ++j) acc[i][j] = zero;
  bf16x8 wb[3][4];
  #pragma unroll
  for (int ni = 0; ni < 4; ++ni) wb[0][ni] = ldb16(wbase + (size_t)ni*16*256 + 0*32);
  #pragma unroll
  for (int ni = 0; ni < 4; ++ni) wb[1][ni] = ldb16(wbase + (size_t)ni*16*256 + 1*32);
  __builtin_amdgcn_sched_barrier(0);
  #pragma unroll
  for (int kt = 0; kt < 8; ++kt) {
    if (kt < 6) {
      #pragma unroll
      for (int ni = 0; ni < 4; ++ni)
        wb[(kt+2)%3][ni] = ldb16(wbase + (size_t)ni*16*256 + (kt+2)*32);
    }
    __builtin_amdgcn_sched_barrier(0);
    bf16x8 af[2];
    #pragma unroll
    for (int mi = 0; mi < 2; ++mi)
      af[mi] = ldb16(&sA[(mi*16 + fr)*LDT + kt*32 + quad*8]);
    #pragma unroll
    for (int mi = 0; mi < 2; ++mi)
      #pragma unroll
      for (int ni = 0; ni < 4; ++ni)
        acc[mi][ni] = __builtin_amdgcn_mfma_f32_16x16x32_bf16(
            af[mi], wb[kt%3][ni], acc[mi][ni], 0, 0, 0);
  }
  #pragma unroll
  for (int mi = 0; mi < 2; ++mi)
    #pragma unroll
    for (int ni = 0; ni < 4; ++ni)
      #pragma unroll
      for (int r = 0; r < 4; ++r) {
        int grow = m0 + mi*16 + quad*4 + r;
        int gcol = wn + ni*16 + fr;
        G[(size_t)grow * 256 + gcol] = f2bf(acc[mi][ni][r]);
      }
}

// ---------------- fused: out[orig] = relu(relu(interp + ft[orig]@W1b) @ W2) ----------------
// ROUND-10 = round-9 (asm-pinned loads, drain-only waits; best measured) plus:
//  (1) XCD-aware bijective block swizzle (T1): 1024 blocks % 8 == 0, so
//      swz = (bid&7)*128 + (bid>>3).  Adjacent sorted-row tiles (which gather
//      overlapping G rows / ft neighborhoods) now colocate on one XCD's L2
//      instead of being round-robined across 8 non-coherent L2s.
//  (2) s_orig[64] LDS stage of the sorted->orig row map: the out-epilogue's
//      16 dependent flat loads of st[lr].w (on the critical tail) become
//      4B ds_reads.  +256 B LDS; still 3 blocks/CU.
// Numerics bit-identical to round 9.
__global__ __launch_bounds__(512, 4) void fused_mlp(const float* __restrict__ ft,
    const unsigned short* __restrict__ G, const int* __restrict__ idxb,
    const float* __restrict__ wgtb, const float4* __restrict__ stgt,
    const unsigned short* __restrict__ w1bt, const unsigned short* __restrict__ w2t,
    float* __restrict__ out) {
  constexpr int LDI = 264;
  constexpr int LDF = 136;
  __shared__ __attribute__((aligned(16))) unsigned short sI[64 * LDI];
  __shared__ __attribute__((aligned(16))) unsigned short sF[64 * LDF];
  __shared__ int s_orig[64];
  int tid = threadIdx.x;
  // XCD swizzle: grid = 1024 (multiple of 8) -> simple bijective form valid.
  int bid = blockIdx.x;
  int swz = (bid & 7) * 128 + (bid >> 3);
  int row0 = swz * 64;          // global sorted row
  int b = row0 >> 14;
  const float4* st = stgt + ((size_t)b << 14) + (row0 & (NT - 1));
  const float* ftb = ft + (size_t)b * NT * CT;
  float* outb = out + (size_t)b * NT * NOUT;
  int wave = tid >> 6, lane = tid & 63;
  int wn = wave * 32;                 // 8 waves x 32 cols = 256
  int fr = lane & 15, quad = lane >> 4;

  // ---- A. dependency roots
  int r = tid >> 3, seg = tid & 7;
  const int* ip = idxb + (size_t)(row0 + r) * 3;
  const float* wp = wgtb + (size_t)(row0 + r) * 3;
  int g0i = ip[0], g1i = ip[1], g2i = ip[2];
  float w0 = wp[0], w1v = wp[1], w2v = wp[2];
  int rA = tid >> 4;
  int rB = rA + 32;
  int orig0 = __float_as_int(st[rA].w);
  int orig1 = __float_as_int(st[rB].w);
  if (tid < 64) s_orig[tid] = __float_as_int(st[tid].w);

  // ---- B. pinned issue: 12 gather + 4 ft loads (all fly together)
  const unsigned short* Gb = G + ((size_t)b << 20);
  const unsigned short* g0 = Gb + ((size_t)g0i << 8) + seg * 32;
  const unsigned short* g1 = Gb + ((size_t)g1i << 8) + seg * 32;
  const unsigned short* g2 = Gb + ((size_t)g2i << 8) + seg * 32;
  int k8 = (tid & 15) * 8;
  const float* srcA = ftb + (size_t)orig0 * CT + k8;
  const float* srcB = ftb + (size_t)orig1 * CT + k8;

  ushortx8 a0, a1, a2, a3, c0, c1, c2, c3, e0, e1, e2, e3;
  GLD16(a0, g0, 0);  GLD16(a1, g0, 16);  GLD16(a2, g0, 32);  GLD16(a3, g0, 48);
  GLD16(c0, g1, 0);  GLD16(c1, g1, 16);  GLD16(c2, g1, 32);  GLD16(c3, g1, 48);
  GLD16(e0, g2, 0);  GLD16(e1, g2, 16);  GLD16(e2, g2, 32);  GLD16(e3, g2, 48);
  floatx4 fa0, fa1, fb0, fb1;
  GLD16(fa0, srcA, 0);  GLD16(fa1, srcA, 16);
  GLD16(fb0, srcB, 0);  GLD16(fb1, srcB, 16);

  // drain EVERYTHING (no counting assumptions); tie all 16 values so every
  // consumer data-depends on this wait; fence the scheduler (rule #18).
  asm volatile("s_waitcnt vmcnt(0)"
               : "+v"(a0), "+v"(a1), "+v"(a2), "+v"(a3),
                 "+v"(c0), "+v"(c1), "+v"(c2), "+v"(c3),
                 "+v"(e0), "+v"(e1), "+v"(e2), "+v"(e3),
                 "+v"(fa0), "+v"(fa1), "+v"(fb0), "+v"(fb1));
  __builtin_amdgcn_sched_barrier(0);

  // ---- C. pinned issue of 8 wb1 loads; complete under combine + barrier
  const unsigned short* w1p0 = w1bt + (size_t)(wn + fr) * CT + quad * 8;
  const unsigned short* w1p1 = w1bt + (size_t)(wn + 16 + fr) * CT + quad * 8;
  bf16x8 wb1[2][4];
  GLD16(wb1[0][0], w1p0, 0);   GLD16(wb1[0][1], w1p0, 64);
  GLD16(wb1[0][2], w1p0, 128); GLD16(wb1[0][3], w1p0, 192);
  GLD16(wb1[1][0], w1p1, 0);   GLD16(wb1[1][1], w1p1, 64);
  GLD16(wb1[1][2], w1p1, 128); GLD16(wb1[1][3], w1p1, 192);

  // ---- D. interp combine + LDS write (gather values resident)
  {
    unsigned short* dst = &sI[r * LDI + seg * 32];
    *(ushortx8*)(dst + 0)  = wsum8(a0, c0, e0, w0, w1v, w2v);
    *(ushortx8*)(dst + 8)  = wsum8(a1, c1, e1, w0, w1v, w2v);
    *(ushortx8*)(dst + 16) = wsum8(a2, c2, e2, w0, w1v, w2v);
    *(ushortx8*)(dst + 24) = wsum8(a3, c3, e3, w0, w1v, w2v);
  }
  // ---- E. ft cvt + LDS write
  {
    ushortx8 o;
    o[0]=f2bf(fa0[0]); o[1]=f2bf(fa0[1]); o[2]=f2bf(fa0[2]); o[3]=f2bf(fa0[3]);
    o[4]=f2bf(fa1[0]); o[5]=f2bf(fa1[1]); o[6]=f2bf(fa1[2]); o[7]=f2bf(fa1[3]);
    *(ushortx8*)&sF[rA * LDF + k8] = o;
    ushortx8 p;
    p[0]=f2bf(fb0[0]); p[1]=f2bf(fb0[1]); p[2]=f2bf(fb0[2]); p[3]=f2bf(fb0[3]);
    p[4]=f2bf(fb1[0]); p[5]=f2bf(fb1[1]); p[6]=f2bf(fb1[2]); p[7]=f2bf(fb1[3]);
    *(ushortx8*)&sF[rB * LDF + k8] = p;
  }
  __syncthreads();

  // safety drain before first wb1 use (free if the barrier already drained)
  asm volatile("s_waitcnt vmcnt(0)"
               : "+v"(wb1[0][0]), "+v"(wb1[0][1]), "+v"(wb1[0][2]), "+v"(wb1[0][3]),
                 "+v"(wb1[1][0]), "+v"(wb1[1][1]), "+v"(wb1[1][2]), "+v"(wb1[1][3]));
  __builtin_amdgcn_sched_barrier(0);

  floatx4 zero = {0.f, 0.f, 0.f, 0.f};
  floatx4 acc[4][2];
  #pragma unroll
  for (int i = 0; i < 4; ++i)
    #pragma unroll
    for (int j = 0; j < 2; ++j) acc[i][j] = zero;

  // ---- phase 1: ft @ W1b (K=128); B in registers (asm defs), A from LDS
  #pragma unroll
  for (int kt = 0; kt < 4; ++kt) {
    bf16x8 af[4];
    #pragma unroll
    for (int mi = 0; mi < 4; ++mi)
      af[mi] = ldb16(&sF[(mi*16 + fr)*LDF + kt*32 + quad*8]);
    #pragma unroll
    for (int mi = 0; mi < 4; ++mi)
      #pragma unroll
      for (int ni = 0; ni < 2; ++ni)
        acc[mi][ni] = __builtin_amdgcn_mfma_f32_16x16x32_bf16(
            af[mi], wb1[ni][kt], acc[mi][ni], 0, 0, 0);
  }

  // ---- F. pinned issue of 16 wb2 loads; complete under epilogue + barrier
  const unsigned short* w2p0 = w2t + (size_t)(wn + fr) * NOUT + quad * 8;
  const unsigned short* w2p1 = w2t + (size_t)(wn + 16 + fr) * NOUT + quad * 8;
  bf16x8 wb2[2][8];
  GLD16(wb2[0][0], w2p0, 0);   GLD16(wb2[0][1], w2p0, 64);
  GLD16(wb2[0][2], w2p0, 128); GLD16(wb2[0][3], w2p0, 192);
  GLD16(wb2[0][4], w2p0, 256); GLD16(wb2[0][5], w2p0, 320);
  GLD16(wb2[0][6], w2p0, 384); GLD16(wb2[0][7], w2p0, 448);
  GLD16(wb2[1][0], w2p1, 0);   GLD16(wb2[1][1], w2p1, 64);
  GLD16(wb2[1][2], w2p1, 128); GLD16(wb2[1][3], w2p1, 192);
  GLD16(wb2[1][4], w2p1, 256); GLD16(wb2[1][5], w2p1, 320);
  GLD16(wb2[1][6], w2p1, 384); GLD16(wb2[1][7], w2p1, 448);

  // ---- phase-1 epilogue: T = relu(acc + interp) bf16, in-place in sI
  #pragma unroll
  for (int mi = 0; mi < 4; ++mi)
    #pragma unroll
    for (int ni = 0; ni < 2; ++ni)
      #pragma unroll
      for (int rr = 0; rr < 4; ++rr) {
        int lr = mi*16 + quad*4 + rr;
        int lc = wn + ni*16 + fr;
        float v = acc[mi][ni][rr] + bf2f(sI[lr * LDI + lc]);
        sI[lr * LDI + lc] = f2bf(fmaxf(v, 0.f));
      }
  __syncthreads();

  // safety drain before first wb2 use (free if the barrier already drained)
  asm volatile("s_waitcnt vmcnt(0)"
               : "+v"(wb2[0][0]), "+v"(wb2[0][1]), "+v"(wb2[0][2]), "+v"(wb2[0][3]),
                 "+v"(wb2[0][4]), "+v"(wb2[0][5]), "+v"(wb2[0][6]), "+v"(wb2[0][7]),
                 "+v"(wb2[1][0]), "+v"(wb2[1][1]), "+v"(wb2[1][2]), "+v"(wb2[1][3]),
                 "+v"(wb2[1][4]), "+v"(wb2[1][5]), "+v"(wb2[1][6]), "+v"(wb2[1][7]));
  __builtin_amdgcn_sched_barrier(0);

  // ---- phase 2: T @ W2 (K=256); B in registers (asm defs), A from LDS
  #pragma unroll
  for (int i = 0; i < 4; ++i)
    #pragma unroll
    for (int j = 0; j < 2; ++j) acc[i][j] = zero;
  #pragma unroll
  for (int kt = 0; kt < 8; ++kt) {
    bf16x8 af[4];
    #pragma unroll
    for (int mi = 0; mi < 4; ++mi)
      af[mi] = ldb16(&sI[(mi*16 + fr)*LDI + kt*32 + quad*8]);
    #pragma unroll
    for (int mi = 0; mi < 4; ++mi)
      #pragma unroll
      for (int ni = 0; ni < 2; ++ni)
        acc[mi][ni] = __builtin_amdgcn_mfma_f32_16x16x32_bf16(
            af[mi], wb2[ni][kt], acc[mi][ni], 0, 0, 0);
  }
  // ---- out epilogue: scatter rows back to original positions (orig from LDS)
  #pragma unroll
  for (int mi = 0; mi < 4; ++mi)
    #pragma unroll
    for (int rr = 0; rr < 4; ++rr) {
      int lr = mi*16 + quad*4 + rr;
      int orig = s_orig[lr];
      float* orow = outb + (size_t)orig * NOUT;
      #pragma unroll
      for (int ni = 0; ni < 2; ++ni)
        orow[wn + ni*16 + fr] = fmaxf(acc[mi][ni][rr], 0.f);
    }
}

extern "C" void kernel_launch(void* const* d_in, const int* in_sizes, int n_in,
                              void* d_out, int out_size, void* d_ws, size_t ws_size,
                              hipStream_t stream) {
  (void)in_sizes; (void)n_in; (void)out_size; (void)ws_size;
  const float* xyzt = (const float*)d_in[0];
  const float* xyzs = (const float*)d_in[1];
  const float* ft   = (const float*)d_in[2];
  const float* fs   = (const float*)d_in[3];
  const float* w1   = (const float*)d_in[4];
  const float* w2   = (const float*)d_in[5];

  char* p = (char*)d_ws;
  unsigned short* w1at = (unsigned short*)p; p += (size_t)256*256*2;
  unsigned short* w1bt = (unsigned short*)p; p += (size_t)256*128*2;
  unsigned short* w2t  = (unsigned short*)p; p += (size_t)256*256*2;
  int*   idxb = (int*)p;   p += (size_t)MTOT*3*4;
  float* wgtb = (float*)p; p += (size_t)MTOT*3*4;
  unsigned short* G = (unsigned short*)p; p += (size_t)BS*NS*NOUT*2;
  float4* bsrc = (float4*)p; p += (size_t)BS*NS*16;
  float4* stgt = (float4*)p; p += (size_t)BS*NT*16;
  int*    soff = (int*)p;

  hipLaunchKernelGGL(prep_kernel, dim3(8 + 64), dim3(1024), 0, stream,
                     xyzs, xyzt, w1, w2, bsrc, soff, stgt, w1at, w1bt, w2t);
  hipLaunchKernelGGL(nn_kernel, dim3(512), dim3(256), 0, stream, stgt, bsrc, soff, idxb, wgtb);
  hipLaunchKernelGGL(gemm_g, dim3(BS*NS/32), dim3(256), 0, stream, fs, w1at, G);
  hipLaunchKernelGGL(fused_mlp, dim3(MTOT/64), dim3(512), 0, stream,
                     ft, G, idxb, wgtb, stgt, w1bt, w2t, (float*)d_out);
}

// Round 11
// 189.602 us; speedup vs baseline: 1.0770x; 1.0770x over previous
//
#include <hip/hip_runtime.h>
#include <hip/hip_bf16.h>
#include <stdint.h>

#define BS 4
#define NS 4096
#define NT 16384
#define CT 128
#define NOUT 256
#define MTOT (BS*NT) // 65536
#define GR 8
#define NC (GR*GR*GR)
#define HCELL 0.125f

typedef __attribute__((ext_vector_type(4))) float floatx4;
typedef __attribute__((ext_vector_type(8))) unsigned short ushortx8;
typedef __attribute__((ext_vector_type(8))) __bf16 bf16x8;

__device__ __forceinline__ unsigned short f2bf(float f) {
  unsigned int u = __builtin_bit_cast(unsigned int, f);
  u += 0x7FFFu + ((u >> 16) & 1u);
  return (unsigned short)(u >> 16);
}
__device__ __forceinline__ float bf2f(unsigned short u) {
  return __builtin_bit_cast(float, ((unsigned int)u) << 16);
}
__device__ __forceinline__ int cell_of(float x) {
  int c = (int)(x * 8.0f);
  return min(7, max(0, c));
}
__device__ __forceinline__ bf16x8 ldb16(const unsigned short* p) {
  return __builtin_bit_cast(bf16x8, *(const ushortx8*)p);
}
__device__ __forceinline__ ushortx8 wsum8(ushortx8 a, ushortx8 c, ushortx8 e,
                                          float w0, float w1v, float w2v) {
  ushortx8 o;
  #pragma unroll
  for (int q = 0; q < 8; ++q)
    o[q] = f2bf(w0*bf2f(a[q]) + w1v*bf2f(c[q]) + w2v*bf2f(e[q]));
  return o;
}

// pinned 16B global load: asm volatile cannot be sunk/serialized by the scheduler
#define GLD16(dst, ptr, off) \
  asm volatile("global_load_dwordx4 %0, %1, off offset:" #off \
               : "=&v"(dst) : "v"(ptr))

// ---------------- prep: bucket sources + sort targets + weight transpose ----------------
__global__ __launch_bounds__(1024) void prep_kernel(
    const float* __restrict__ xyzs, const float* __restrict__ xyzt,
    const float* __restrict__ w1, const float* __restrict__ w2,
    float4* __restrict__ bsrc, int* __restrict__ soff, float4* __restrict__ stgt,
    unsigned short* __restrict__ w1at, unsigned short* __restrict__ w1bt,
    unsigned short* __restrict__ w2t) {
  int bid = blockIdx.x, tid = threadIdx.x;
  if (bid < 8) {
    __shared__ int cnt[NC];
    __shared__ int wtot[16];
    int b = bid & 3;
    bool isrc = bid < 4;
    int per = isrc ? (NS >> 10) : (NT >> 10);
    const float* in = isrc ? xyzs + (size_t)b * NS * 3 : xyzt + (size_t)b * NT * 3;
    float4* outp = isrc ? bsrc + (size_t)b * NS : stgt + (size_t)b * NT;
    if (tid < NC) cnt[tid] = 0;
    __syncthreads();
    for (int k = 0; k < per; ++k) {
      int p = k * 1024 + tid;
      float x = in[3*p], y = in[3*p+1], z = in[3*p+2];
      int c = (cell_of(z) * GR + cell_of(y)) * GR + cell_of(x);
      atomicAdd(&cnt[c], 1);
    }
    __syncthreads();
    int l = tid & 63, w = tid >> 6;
    int v = (tid < NC) ? cnt[tid] : 0;
    #pragma unroll
    for (int d = 1; d < 64; d <<= 1) {
      int t = __shfl_up(v, d);
      if (l >= d) v += t;
    }
    if (l == 63 && w < 8) wtot[w] = v;
    __syncthreads();
    if (w == 0 && l < 8) {
      int s = wtot[l];
      #pragma unroll
      for (int d = 1; d < 8; d <<= 1) {
        int t = __shfl_up(s, d);
        if (l >= d) s += t;
      }
      wtot[l] = s;
    }
    __syncthreads();
    if (tid < NC) {
      int incl = v + (w > 0 ? wtot[w-1] : 0);
      int excl = incl - cnt[tid];
      cnt[tid] = excl;
      if (isrc) soff[b * (NC + 1) + tid] = excl;
    }
    if (isrc && tid == 0) soff[b * (NC + 1) + NC] = NS;
    __syncthreads();
    for (int k = 0; k < per; ++k) {
      int p = k * 1024 + tid;
      float x = in[3*p], y = in[3*p+1], z = in[3*p+2];
      int c = (cell_of(z) * GR + cell_of(y)) * GR + cell_of(x);
      int slot = atomicAdd(&cnt[c], 1);
      outp[slot] = make_float4(x, y, z, __int_as_float(p));
    }
  } else {
    int i = (bid - 8) * 1024 + tid;  // i < 65536
    int n = i >> 8, k = i & 255;
    w1at[i] = f2bf(w1[k * NOUT + n]);
    w2t[i]  = f2bf(w2[k * NOUT + n]);
    if (i < 256 * 128) {
      int n2 = i >> 7, k2 = i & 127;
      w1bt[i] = f2bf(w1[(256 + k2) * NOUT + n2]);
    }
  }
}

// ---------------- three_nn helpers ----------------
__device__ __forceinline__ void ins3(float sc, int jj,
    float& d0, float& d1, float& d2, int& i0, int& i1, int& i2) {
  bool l0 = sc < d0, l1 = sc < d1, l2 = sc < d2;
  d2 = l1 ? d1 : (l2 ? sc : d2);
  i2 = l1 ? i1 : (l2 ? jj : i2);
  d1 = l0 ? d0 : (l1 ? sc : d1);
  i1 = l0 ? i0 : (l1 ? jj : i1);
  d0 = l0 ? sc : d0;
  i0 = l0 ? jj : i0;
}

__device__ __forceinline__ void pair_merge(float& d0, float& d1, float& d2,
                                           int& i0, int& i1, int& i2,
                                           int delta, int sub) {
  float e0 = __shfl_xor(d0, delta);
  float e1 = __shfl_xor(d1, delta);
  float e2 = __shfl_xor(d2, delta);
  int   y0 = __shfl_xor(i0, delta);
  int   y1 = __shfl_xor(i1, delta);
  int   y2 = __shfl_xor(i2, delta);
  float a0,a1,a2,b0,b1,b2; int x0,x1,x2,z0,z1,z2;
  if ((sub & delta) == 0) { a0=d0;a1=d1;a2=d2; x0=i0;x1=i1;x2=i2;
                            b0=e0;b1=e1;b2=e2; z0=y0;z1=y1;z2=y2; }
  else                    { a0=e0;a1=e1;a2=e2; x0=y0;x1=y1;x2=y2;
                            b0=d0;b1=d1;b2=d2; z0=i0;z1=i1;z2=i2; }
  bool t = a0 <= b0;
  d0 = t ? a0 : b0; i0 = t ? x0 : z0;
  float na0 = t ? a1 : a0; int nx0 = t ? x1 : x0;
  float na1 = t ? a2 : a1; int nx1 = t ? x2 : x1;
  float nb0 = t ? b0 : b1; int nz0 = t ? z0 : z1;
  float nb1 = t ? b1 : b2; int nz1 = t ? z1 : z2;
  t = na0 <= nb0;
  d1 = t ? na0 : nb0; i1 = t ? nx0 : nz0;
  float ma0 = t ? na1 : na0; int mx0 = t ? nx1 : nx0;
  float mb0 = t ? nb0 : nb1; int mz0 = t ? nz0 : nz1;
  t = ma0 <= mb0;
  d2 = t ? ma0 : mb0; i2 = t ? mx0 : mz0;
}

// round-6 version (part of best-measured totals)
__global__ __launch_bounds__(256) void nn_kernel(const float4* __restrict__ stgt,
    const float4* __restrict__ bsrc, const int* __restrict__ soff,
    int* __restrict__ idx_out, float* __restrict__ w_out) {
  __shared__ float4 s_src[NS];
  __shared__ int s_off[NC + 1];
  __shared__ float4 s_badq[128];
  __shared__ int s_badn;
  int tid = threadIdx.x;
  int b = blockIdx.x >> 7;
  int tseg = blockIdx.x & 127;
  if (tid == 0) s_badn = 0;
  for (int i = tid; i < NS; i += 256) s_src[i] = bsrc[(size_t)b * NS + i];
  for (int i = tid; i < NC + 1; i += 256) s_off[i] = soff[b * (NC + 1) + i];
  __syncthreads();
  int tpair = tid >> 1, half = tid & 1;
  float4 tg = stgt[(size_t)b * NT + tseg * 128 + tpair];
  float tx = tg.x, ty = tg.y, tz = tg.z;
  int cx = cell_of(tx), cy = cell_of(ty), cz = cell_of(tz);
  int wx = min(max(cx, 1), 6) - 1;
  int wy = min(max(cy, 1), 6) - 1;
  int wz = min(max(cz, 1), 6) - 1;
  float d0 = 1e30f, d1 = 1e30f, d2 = 1e30f;
  int i0 = 0, i1 = 0, i2 = 0;
  for (int r = half; r < 9; r += 2) {
    int ez = wz + r / 3, ey = wy + r % 3;
    int rowc = (ez * GR + ey) * GR + wx;
    int lo = s_off[rowc], hi = s_off[rowc + 3];
    for (int p = lo; p < hi; ++p) {
      float4 s = s_src[p];
      float dx = tx - s.x, dy = ty - s.y, dz = tz - s.z;
      float q = dx*dx + dy*dy + dz*dz;
      ins3(q, __float_as_int(s.w), d0, d1, d2, i0, i1, i2);
    }
  }
  pair_merge(d0, d1, d2, i0, i1, i2, 1, half);
  float clx = fminf(wx > 0 ? tx - wx * HCELL : 1e30f,
                    wx + 3 < GR ? (wx + 3) * HCELL - tx : 1e30f);
  float cly = fminf(wy > 0 ? ty - wy * HCELL : 1e30f,
                    wy + 3 < GR ? (wy + 3) * HCELL - ty : 1e30f);
  float clz = fminf(wz > 0 ? tz - wz * HCELL : 1e30f,
                    wz + 3 < GR ? (wz + 3) * HCELL - tz : 1e30f);
  float cl = fminf(clx, fminf(cly, clz));
  bool bad = d2 > cl * cl;
  if (half == 0) {
    if (bad) {
      int slot = atomicAdd(&s_badn, 1);
      s_badq[slot] = make_float4(tx, ty, tz, __int_as_float(tseg * 128 + tpair));
    } else {
      float r0 = fmaxf(sqrtf(d0), 1e-10f);
      float r1 = fmaxf(sqrtf(d1), 1e-10f);
      float r2 = fmaxf(sqrtf(d2), 1e-10f);
      float v0 = 1.f/r0, v1 = 1.f/r1, v2 = 1.f/r2;
      float sc = 1.f / ((v0 + v1 + v2) * (1.f + 1e-6f));
      size_t o = ((size_t)b * NT + tseg * 128 + tpair) * 3;
      idx_out[o] = i0; idx_out[o+1] = i1; idx_out[o+2] = i2;
      w_out[o] = v0*sc; w_out[o+1] = v1*sc; w_out[o+2] = v2*sc;
    }
  }
  __syncthreads();
  int nbad = s_badn;
  int wv = tid >> 6, ln = tid & 63;
  for (int e = wv; e < nbad; e += 4) {
    float4 tq = s_badq[e];
    float qx = tq.x, qy = tq.y, qz = tq.z;
    float f0 = 1e30f, f1 = 1e30f, f2 = 1e30f;
    int   j0 = 0, j1 = 0, j2 = 0;
    for (int p = ln; p < NS; p += 64) {
      float4 s = s_src[p];
      float dx = qx - s.x, dy = qy - s.y, dz = qz - s.z;
      float q = dx*dx + dy*dy + dz*dz;
      ins3(q, __float_as_int(s.w), f0, f1, f2, j0, j1, j2);
    }
    #pragma unroll
    for (int delta = 1; delta <= 32; delta <<= 1)
      pair_merge(f0, f1, f2, j0, j1, j2, delta, ln);
    if (ln == 0) {
      float r0 = fmaxf(sqrtf(f0), 1e-10f);
      float r1 = fmaxf(sqrtf(f1), 1e-10f);
      float r2 = fmaxf(sqrtf(f2), 1e-10f);
      float v0 = 1.f/r0, v1 = 1.f/r1, v2 = 1.f/r2;
      float sc = 1.f / ((v0 + v1 + v2) * (1.f + 1e-6f));
      size_t o = ((size_t)b * NT + __float_as_int(tq.w)) * 3;
      idx_out[o] = j0; idx_out[o+1] = j1; idx_out[o+2] = j2;
      w_out[o] = v0*sc; w_out[o+1] = v1*sc; w_out[o+2] = v2*sc;
    }
  }
}

// ---------------- G = fs @ W1a  (bf16 out, no relu) ---------------- (round-6 version)
__global__ __launch_bounds__(256, 4) void gemm_g(const float* __restrict__ fs,
    const unsigned short* __restrict__ w1at, unsigned short* __restrict__ G) {
  constexpr int LDT = 264;  // 256 + 8 pad
  __shared__ __attribute__((aligned(16))) unsigned short sA[32 * LDT];
  int tid = threadIdx.x;
  int m0 = blockIdx.x * 32;
  int wave = tid >> 6, lane = tid & 63;
  int wn = wave * 64;
  int fr = lane & 15, quad = lane >> 4;
  const unsigned short* wbase = w1at + (size_t)(wn + fr) * 256 + quad * 8;
  #pragma unroll
  for (int i = 0; i < 4; ++i) {
    int u = tid + 256 * i;
    int r = u >> 5, k8 = (u & 31) * 8;
    const float* src = fs + (size_t)(m0 + r) * 256 + k8;
    float4 f0 = *(const float4*)src;
    float4 f1 = *(const float4*)(src + 4);
    ushortx8 o;
    o[0]=f2bf(f0.x); o[1]=f2bf(f0.y); o[2]=f2bf(f0.z); o[3]=f2bf(f0.w);
    o[4]=f2bf(f1.x); o[5]=f2bf(f1.y); o[6]=f2bf(f1.z); o[7]=f2bf(f1.w);
    *(ushortx8*)&sA[r * LDT + k8] = o;
  }
  __syncthreads();
  floatx4 zero = {0.f, 0.f, 0.f, 0.f};
  floatx4 acc[2][4];
  #pragma unroll
  for (int i = 0; i < 2; ++i)
    #pragma unroll
    for (int j = 0; j < 4; ++j) acc[i][j] = zero;
  bf16x8 wb[3][4];
  #pragma unroll
  for (int ni = 0; ni < 4; ++ni) wb[0][ni] = ldb16(wbase + (size_t)ni*16*256 + 0*32);
  #pragma unroll
  for (int ni = 0; ni < 4; ++ni) wb[1][ni] = ldb16(wbase + (size_t)ni*16*256 + 1*32);
  __builtin_amdgcn_sched_barrier(0);
  #pragma unroll
  for (int kt = 0; kt < 8; ++kt) {
    if (kt < 6) {
      #pragma unroll
      for (int ni = 0; ni < 4; ++ni)
        wb[(kt+2)%3][ni] = ldb16(wbase + (size_t)ni*16*256 + (kt+2)*32);
    }
    __builtin_amdgcn_sched_barrier(0);
    bf16x8 af[2];
    #pragma unroll
    for (int mi = 0; mi < 2; ++mi)
      af[mi] = ldb16(&sA[(mi*16 + fr)*LDT + kt*32 + quad*8]);
    #pragma unroll
    for (int mi = 0; mi < 2; ++mi)
      #pragma unroll
      for (int ni = 0; ni < 4; ++ni)
        acc[mi][ni] = __builtin_amdgcn_mfma_f32_16x16x32_bf16(
            af[mi], wb[kt%3][ni], acc[mi][ni], 0, 0, 0);
  }
  #pragma unroll
  for (int mi = 0; mi < 2; ++mi)
    #pragma unroll
    for (int ni = 0; ni < 4; ++ni)
      #pragma unroll
      for (int r = 0; r < 4; ++r) {
        int grow = m0 + mi*16 + quad*4 + r;
        int gcol = wn + ni*16 + fr;
        G[(size_t)grow * 256 + gcol] = f2bf(acc[mi][ni][r]);
      }
}

// ---------------- fused: out[orig] = relu(relu(interp + ft[orig]@W1b) @ W2) ----------------
// FINAL = round-9 exactly (best measured: total 190.2 us, fused 47.4-49.4 us).
// asm-pinned loads with DRAIN-ONLY waits: 12 gather + 4 ft loads fly together
// behind one tied vmcnt(0); wb1/wb2 issue-early and complete under barriers.
// Round-10's XCD swizzle REGRESSED (FETCH +24%, WRITE +38%: it destroyed the
// temporal locality of the default dispatch order -- concurrent blocks spanned
// all 4 batches) and is reverted.  linear blockIdx order is optimal here.
__global__ __launch_bounds__(512, 4) void fused_mlp(const float* __restrict__ ft,
    const unsigned short* __restrict__ G, const int* __restrict__ idxb,
    const float* __restrict__ wgtb, const float4* __restrict__ stgt,
    const unsigned short* __restrict__ w1bt, const unsigned short* __restrict__ w2t,
    float* __restrict__ out) {
  constexpr int LDI = 264;
  constexpr int LDF = 136;
  __shared__ __attribute__((aligned(16))) unsigned short sI[64 * LDI];
  __shared__ __attribute__((aligned(16))) unsigned short sF[64 * LDF];
  int tid = threadIdx.x;
  int row0 = blockIdx.x * 64;   // global sorted row (linear order: optimal)
  int b = row0 >> 14;
  const float4* st = stgt + ((size_t)b << 14) + (row0 & (NT - 1));
  const float* ftb = ft + (size_t)b * NT * CT;
  float* outb = out + (size_t)b * NT * NOUT;
  int wave = tid >> 6, lane = tid & 63;
  int wn = wave * 32;                 // 8 waves x 32 cols = 256
  int fr = lane & 15, quad = lane >> 4;

  // ---- A. dependency roots
  int r = tid >> 3, seg = tid & 7;
  const int* ip = idxb + (size_t)(row0 + r) * 3;
  const float* wp = wgtb + (size_t)(row0 + r) * 3;
  int g0i = ip[0], g1i = ip[1], g2i = ip[2];
  float w0 = wp[0], w1v = wp[1], w2v = wp[2];
  int rA = tid >> 4;
  int rB = rA + 32;
  int orig0 = __float_as_int(st[rA].w);
  int orig1 = __float_as_int(st[rB].w);

  // ---- B. pinned issue: 12 gather + 4 ft loads (all fly together)
  const unsigned short* Gb = G + ((size_t)b << 20);
  const unsigned short* g0 = Gb + ((size_t)g0i << 8) + seg * 32;
  const unsigned short* g1 = Gb + ((size_t)g1i << 8) + seg * 32;
  const unsigned short* g2 = Gb + ((size_t)g2i << 8) + seg * 32;
  int k8 = (tid & 15) * 8;
  const float* srcA = ftb + (size_t)orig0 * CT + k8;
  const float* srcB = ftb + (size_t)orig1 * CT + k8;

  ushortx8 a0, a1, a2, a3, c0, c1, c2, c3, e0, e1, e2, e3;
  GLD16(a0, g0, 0);  GLD16(a1, g0, 16);  GLD16(a2, g0, 32);  GLD16(a3, g0, 48);
  GLD16(c0, g1, 0);  GLD16(c1, g1, 16);  GLD16(c2, g1, 32);  GLD16(c3, g1, 48);
  GLD16(e0, g2, 0);  GLD16(e1, g2, 16);  GLD16(e2, g2, 32);  GLD16(e3, g2, 48);
  floatx4 fa0, fa1, fb0, fb1;
  GLD16(fa0, srcA, 0);  GLD16(fa1, srcA, 16);
  GLD16(fb0, srcB, 0);  GLD16(fb1, srcB, 16);

  // drain EVERYTHING (no counting assumptions); tie all 16 values so every
  // consumer data-depends on this wait; fence the scheduler (rule #18).
  asm volatile("s_waitcnt vmcnt(0)"
               : "+v"(a0), "+v"(a1), "+v"(a2), "+v"(a3),
                 "+v"(c0), "+v"(c1), "+v"(c2), "+v"(c3),
                 "+v"(e0), "+v"(e1), "+v"(e2), "+v"(e3),
                 "+v"(fa0), "+v"(fa1), "+v"(fb0), "+v"(fb1));
  __builtin_amdgcn_sched_barrier(0);

  // ---- C. pinned issue of 8 wb1 loads; complete under combine + barrier
  const unsigned short* w1p0 = w1bt + (size_t)(wn + fr) * CT + quad * 8;
  const unsigned short* w1p1 = w1bt + (size_t)(wn + 16 + fr) * CT + quad * 8;
  bf16x8 wb1[2][4];
  GLD16(wb1[0][0], w1p0, 0);   GLD16(wb1[0][1], w1p0, 64);
  GLD16(wb1[0][2], w1p0, 128); GLD16(wb1[0][3], w1p0, 192);
  GLD16(wb1[1][0], w1p1, 0);   GLD16(wb1[1][1], w1p1, 64);
  GLD16(wb1[1][2], w1p1, 128); GLD16(wb1[1][3], w1p1, 192);

  // ---- D. interp combine + LDS write (gather values resident)
  {
    unsigned short* dst = &sI[r * LDI + seg * 32];
    *(ushortx8*)(dst + 0)  = wsum8(a0, c0, e0, w0, w1v, w2v);
    *(ushortx8*)(dst + 8)  = wsum8(a1, c1, e1, w0, w1v, w2v);
    *(ushortx8*)(dst + 16) = wsum8(a2, c2, e2, w0, w1v, w2v);
    *(ushortx8*)(dst + 24) = wsum8(a3, c3, e3, w0, w1v, w2v);
  }
  // ---- E. ft cvt + LDS write
  {
    ushortx8 o;
    o[0]=f2bf(fa0[0]); o[1]=f2bf(fa0[1]); o[2]=f2bf(fa0[2]); o[3]=f2bf(fa0[3]);
    o[4]=f2bf(fa1[0]); o[5]=f2bf(fa1[1]); o[6]=f2bf(fa1[2]); o[7]=f2bf(fa1[3]);
    *(ushortx8*)&sF[rA * LDF + k8] = o;
    ushortx8 p;
    p[0]=f2bf(fb0[0]); p[1]=f2bf(fb0[1]); p[2]=f2bf(fb0[2]); p[3]=f2bf(fb0[3]);
    p[4]=f2bf(fb1[0]); p[5]=f2bf(fb1[1]); p[6]=f2bf(fb1[2]); p[7]=f2bf(fb1[3]);
    *(ushortx8*)&sF[rB * LDF + k8] = p;
  }
  __syncthreads();

  // safety drain before first wb1 use (free if the barrier already drained)
  asm volatile("s_waitcnt vmcnt(0)"
               : "+v"(wb1[0][0]), "+v"(wb1[0][1]), "+v"(wb1[0][2]), "+v"(wb1[0][3]),
                 "+v"(wb1[1][0]), "+v"(wb1[1][1]), "+v"(wb1[1][2]), "+v"(wb1[1][3]));
  __builtin_amdgcn_sched_barrier(0);

  floatx4 zero = {0.f, 0.f, 0.f, 0.f};
  floatx4 acc[4][2];
  #pragma unroll
  for (int i = 0; i < 4; ++i)
    #pragma unroll
    for (int j = 0; j < 2; ++j) acc[i][j] = zero;

  // ---- phase 1: ft @ W1b (K=128); B in registers (asm defs), A from LDS
  #pragma unroll
  for (int kt = 0; kt < 4; ++kt) {
    bf16x8 af[4];
    #pragma unroll
    for (int mi = 0; mi < 4; ++mi)
      af[mi] = ldb16(&sF[(mi*16 + fr)*LDF + kt*32 + quad*8]);
    #pragma unroll
    for (int mi = 0; mi < 4; ++mi)
      #pragma unroll
      for (int ni = 0; ni < 2; ++ni)
        acc[mi][ni] = __builtin_amdgcn_mfma_f32_16x16x32_bf16(
            af[mi], wb1[ni][kt], acc[mi][ni], 0, 0, 0);
  }

  // ---- F. pinned issue of 16 wb2 loads; complete under epilogue + barrier
  const unsigned short* w2p0 = w2t + (size_t)(wn + fr) * NOUT + quad * 8;
  const unsigned short* w2p1 = w2t + (size_t)(wn + 16 + fr) * NOUT + quad * 8;
  bf16x8 wb2[2][8];
  GLD16(wb2[0][0], w2p0, 0);   GLD16(wb2[0][1], w2p0, 64);
  GLD16(wb2[0][2], w2p0, 128); GLD16(wb2[0][3], w2p0, 192);
  GLD16(wb2[0][4], w2p0, 256); GLD16(wb2[0][5], w2p0, 320);
  GLD16(wb2[0][6], w2p0, 384); GLD16(wb2[0][7], w2p0, 448);
  GLD16(wb2[1][0], w2p1, 0);   GLD16(wb2[1][1], w2p1, 64);
  GLD16(wb2[1][2], w2p1, 128); GLD16(wb2[1][3], w2p1, 192);
  GLD16(wb2[1][4], w2p1, 256); GLD16(wb2[1][5], w2p1, 320);
  GLD16(wb2[1][6], w2p1, 384); GLD16(wb2[1][7], w2p1, 448);

  // ---- phase-1 epilogue: T = relu(acc + interp) bf16, in-place in sI
  #pragma unroll
  for (int mi = 0; mi < 4; ++mi)
    #pragma unroll
    for (int ni = 0; ni < 2; ++ni)
      #pragma unroll
      for (int rr = 0; rr < 4; ++rr) {
        int lr = mi*16 + quad*4 + rr;
        int lc = wn + ni*16 + fr;
        float v = acc[mi][ni][rr] + bf2f(sI[lr * LDI + lc]);
        sI[lr * LDI + lc] = f2bf(fmaxf(v, 0.f));
      }
  __syncthreads();

  // safety drain before first wb2 use (free if the barrier already drained)
  asm volatile("s_waitcnt vmcnt(0)"
               : "+v"(wb2[0][0]), "+v"(wb2[0][1]), "+v"(wb2[0][2]), "+v"(wb2[0][3]),
                 "+v"(wb2[0][4]), "+v"(wb2[0][5]), "+v"(wb2[0][6]), "+v"(wb2[0][7]),
                 "+v"(wb2[1][0]), "+v"(wb2[1][1]), "+v"(wb2[1][2]), "+v"(wb2[1][3]),
                 "+v"(wb2[1][4]), "+v"(wb2[1][5]), "+v"(wb2[1][6]), "+v"(wb2[1][7]));
  __builtin_amdgcn_sched_barrier(0);

  // ---- phase 2: T @ W2 (K=256); B in registers (asm defs), A from LDS
  #pragma unroll
  for (int i = 0; i < 4; ++i)
    #pragma unroll
    for (int j = 0; j < 2; ++j) acc[i][j] = zero;
  #pragma unroll
  for (int kt = 0; kt < 8; ++kt) {
    bf16x8 af[4];
    #pragma unroll
    for (int mi = 0; mi < 4; ++mi)
      af[mi] = ldb16(&sI[(mi*16 + fr)*LDI + kt*32 + quad*8]);
    #pragma unroll
    for (int mi = 0; mi < 4; ++mi)
      #pragma unroll
      for (int ni = 0; ni < 2; ++ni)
        acc[mi][ni] = __builtin_amdgcn_mfma_f32_16x16x32_bf16(
            af[mi], wb2[ni][kt], acc[mi][ni], 0, 0, 0);
  }
  // ---- out epilogue: scatter rows back to original positions
  #pragma unroll
  for (int mi = 0; mi < 4; ++mi)
    #pragma unroll
    for (int rr = 0; rr < 4; ++rr) {
      int lr = mi*16 + quad*4 + rr;
      int orig = __float_as_int(st[lr].w);
      float* orow = outb + (size_t)orig * NOUT;
      #pragma unroll
      for (int ni = 0; ni < 2; ++ni)
        orow[wn + ni*16 + fr] = fmaxf(acc[mi][ni][rr], 0.f);
    }
}

extern "C" void kernel_launch(void* const* d_in, const int* in_sizes, int n_in,
                              void* d_out, int out_size, void* d_ws, size_t ws_size,
                              hipStream_t stream) {
  (void)in_sizes; (void)n_in; (void)out_size; (void)ws_size;
  const float* xyzt = (const float*)d_in[0];
  const float* xyzs = (const float*)d_in[1];
  const float* ft   = (const float*)d_in[2];
  const float* fs   = (const float*)d_in[3];
  const float* w1   = (const float*)d_in[4];
  const float* w2   = (const float*)d_in[5];

  char* p = (char*)d_ws;
  unsigned short* w1at = (unsigned short*)p; p += (size_t)256*256*2;
  unsigned short* w1bt = (unsigned short*)p; p += (size_t)256*128*2;
  unsigned short* w2t  = (unsigned short*)p; p += (size_t)256*256*2;
  int*   idxb = (int*)p;   p += (size_t)MTOT*3*4;
  float* wgtb = (float*)p; p += (size_t)MTOT*3*4;
  unsigned short* G = (unsigned short*)p; p += (size_t)BS*NS*NOUT*2;
  float4* bsrc = (float4*)p; p += (size_t)BS*NS*16;
  float4* stgt = (float4*)p; p += (size_t)BS*NT*16;
  int*    soff = (int*)p;

  hipLaunchKernelGGL(prep_kernel, dim3(8 + 64), dim3(1024), 0, stream,
                     xyzs, xyzt, w1, w2, bsrc, soff, stgt, w1at, w1bt, w2t);
  hipLaunchKernelGGL(nn_kernel, dim3(512), dim3(256), 0, stream, stgt, bsrc, soff, idxb, wgtb);
  hipLaunchKernelGGL(gemm_g, dim3(BS*NS/32), dim3(256), 0, stream, fs, w1at, G);
  hipLaunchKernelGGL(fused_mlp, dim3(MTOT/64), dim3(512), 0, stream,
                     ft, G, idxb, wgtb, stgt, w1bt, w2t, (float*)d_out);
}